// Round 10
// baseline (1678.891 us; speedup 1.0000x reference)
//
#include <hip/hip_runtime.h>

typedef float  f32x4  __attribute__((ext_vector_type(4)));
typedef short  s16x8  __attribute__((ext_vector_type(8)));
typedef short  s16x4  __attribute__((ext_vector_type(4)));
typedef _Float16 f16;

namespace {
constexpr int NN = 127, IDIM = 300, HD = 150;
constexpr int GNT = 512;            // big_gemm: 8 waves; wave w owns col-tiles {w+8tt}
constexpr int LNT = 320;            // lights: 5 waves x 2 col-triples, 32 parents/block
constexpr int BCS = 36;             // B col stride (shorts): 18 dw -> 16-bank spread
constexpr int SLAB_SH = 17408;      // 480*36=17280 + pad = 34 KiB
constexpr int SCH = 34;             // 1-KiB staging chunks per slab
constexpr int RSTR = 487;           // leaf recombine stride (odd -> full bank spread)
constexpr int GEMM_LDS = 2 * SLAB_SH * 2;   // 69,632 B (B dbuf only) -> 2 blocks/CU
constexpr int CSTR = 164;           // light chs/hts stride (shorts)

constexpr int W_SH = 10 * SLAB_SH;
constexpr int U_SH = 480 * 160;     // plain [col][k]
constexpr int F_SH = 160 * 160;

// ws: c_all f16 [4096][126][150] (node-1 indexed) | iuo_all f16 [4096][63][456] | slabs
constexpr size_t C_N   = (size_t)4096 * 126 * HD;
constexpr size_t IUO_N = (size_t)4096 * 63 * 456;

__device__ __forceinline__ short f2bf(float f) {
    union { __bf16 b; short s; } u; u.b = (__bf16)f; return u.s;
}
__device__ __forceinline__ float bf2f(short s) {
    union { float f; unsigned u; } v; v.u = ((unsigned)(unsigned short)s) << 16; return v.f;
}
__device__ __forceinline__ short f2h_s(float f) {
    union { f16 h; short s; } u; u.h = (f16)f; return u.s;
}
__device__ __forceinline__ float h2f_s(short s) {
    union { f16 h; short s; } u; u.s = s; return (float)u.h;
}
__device__ __forceinline__ float sig_(float x)  { return 1.0f / (1.0f + __expf(-x)); }
__device__ __forceinline__ float tanh_(float x) { float e = __expf(2.0f * x); return 1.0f - 2.0f / (e + 1.0f); }
__device__ __forceinline__ s16x4 cvt4(float a,float b,float c,float d) {
    return s16x4{ f2bf(a), f2bf(b), f2bf(c), f2bf(d) };
}
__device__ __forceinline__ s16x8 cat(s16x4 lo, s16x4 hi) {
    return __builtin_shufflevector(lo, hi, 0,1,2,3,4,5,6,7);
}
__device__ __forceinline__ s16x8 cvt8f(float4 lo, float4 hi) {
    return cat(cvt4(lo.x,lo.y,lo.z,lo.w), cvt4(hi.x,hi.y,hi.z,hi.w));
}
__device__ __forceinline__ f32x4 MFMA(s16x8 a, s16x8 b, f32x4 c) {
    return __builtin_amdgcn_mfma_f32_16x16x32_bf16(a, b, c, 0, 0, 0);
}

typedef const __attribute__((address_space(1))) unsigned int* gp_t;
typedef __attribute__((address_space(3))) unsigned int* lp_t;
__device__ __forceinline__ void stage_slab(const short* g, short* l, int nch,
                                           int wv, int ln, int nw) {
    const char* gb = (const char*)g;
    char* lb = (char*)l;
    for (int c = wv; c < nch; c += nw)
        __builtin_amdgcn_global_load_lds((gp_t)(gb + c * 1024 + ln * 16),
                                         (lp_t)(lb + c * 1024 + ln * 16), 16, 0, 0);
}
} // namespace

// -------- one-time weight prep: W -> 10 K-chunk slabs [480][36]; U,F plain [col][160] --------
__global__ __launch_bounds__(256)
void prep_w(const float* __restrict__ Wiuo, const float* __restrict__ Uiuo,
            const float* __restrict__ Ufw, short* __restrict__ dst) {
    int i = blockIdx.x * 256 + threadIdx.x;
    short v = 0;
    if (i < W_SH) {
        int kc = i / SLAB_SH, r = i - kc * SLAB_SH;
        if (r < 480 * BCS) {
            int col = r / BCS, j = r - col * BCS;
            int g = col / 160, cp = col - g * 160, k = kc * 32 + j;
            if (cp < HD && j < 32 && k < IDIM) v = f2bf(Wiuo[(size_t)(g*HD + cp)*IDIM + k]);
        }
        dst[i] = v;
    } else if (i < W_SH + U_SH) {
        int q = i - W_SH;
        int col = q / 160, k = q - col * 160;
        int g = col / 160, cp = col - g * 160;
        if (cp < HD && k < HD) v = f2bf(Uiuo[(size_t)(g*HD + cp)*HD + k]);
        dst[i] = v;
    } else if (i < W_SH + U_SH + F_SH) {
        int q = i - W_SH - U_SH;
        int col = q / 160, k = q - col * 160;
        if (col < HD && k < HD) v = f2bf(Ufw[(size_t)col*HD + k]);
        dst[i] = v;
    }
}

// -------- merged projection GEMM, BM=64, 8 waves. A per-lane direct from global x
// (no LDS, no barrier coupling); B via global_load_lds dbuf, ONE barrier per chunk
// draining only the B-DMA issued a full chunk earlier.
// MFMA maps: A row=lane&15, B col=lane&15 (shared lane->k); C/D col=lane&15, row=4*(lane>>4)+reg.
__global__ __launch_bounds__(GNT, 4)
void big_gemm(const float* __restrict__ x, const short* __restrict__ Wsl,
              const float* __restrict__ biuo, float* __restrict__ h_all,
              f16* __restrict__ c_all, f16* __restrict__ iuo_all)
{
    extern __shared__ short smem[];  // [2][SLAB_SH] B double buffer
    short* rs = smem;                // leaf recombine alias (64*487=31168 <= 34816)

    const int t = threadIdx.x;
    const int wv = t >> 6, ln = t & 63, l15 = ln & 15, kg = ln >> 4;
    const int kg8 = kg * 8;
    const int row0 = blockIdx.x * 64;

    // block-uniform level detect (row space ordered leaf-level first)
    int d = 6;
    for (int dd = 0; dd <= 5; ++dd)
        if (row0 >= 4096 * (128 - (2 << dd))) { d = dd; break; }
    const int base = 4096 * (128 - (2 << d));
    const int lg = d, mask = (1 << lg) - 1, start = (1 << lg) - 1;
    const int local0 = row0 - base;

    // per-lane A row pointers: frag row = 16*mt + l15, lane k-offset kg*8
    const float* xr[4];
    #pragma unroll
    for (int mt = 0; mt < 4; ++mt) {
        int lcl = local0 + 16*mt + l15, b = lcl >> lg, s = lcl & mask;
        xr[mt] = x + ((size_t)b * NN + start + s) * IDIM + kg8;
    }

    stage_slab(Wsl, smem, SCH, wv, ln, 8);   // prologue: slab 0

    f32x4 acc[4][4] = {};            // [tt][mt]
    #pragma unroll
    for (int kc = 0; kc < 10; ++kc) {
        __syncthreads();             // drain: B(kc) DMA was issued one full chunk ago
        if (kc < 9)
            stage_slab(Wsl + (kc+1)*SLAB_SH, smem + ((kc+1)&1)*SLAB_SH, SCH, wv, ln, 8);
        const short* Bc = smem + (kc & 1) * SLAB_SH;
        const int kb = kc * 32;
        const bool v0 = (kb + kg8 + 4 <= IDIM);
        const bool v1 = (kb + kg8 + 8 <= IDIM);
        const float4 z = {0.f, 0.f, 0.f, 0.f};

        // B fragments from LDS (4 ds_read_b128)
        s16x8 bf[4];
        #pragma unroll
        for (int tt = 0; tt < 4; ++tt) {
            int ct = wv + 8 * tt;
            int cts = (ct < 30) ? ct : 29;       // dead tiles read tile 29
            const short* pb = &Bc[(cts * 16 + l15) * BCS + kg8];
            bf[tt] = cat(*(const s16x4*)pb, *(const s16x4*)(pb + 4));
        }
        // A batch 1 (mt 0,1): per-lane global loads, in-reg cvt
        float4 lo0 = v0 ? *(const float4*)(xr[0] + kb)     : z;
        float4 hi0 = v1 ? *(const float4*)(xr[0] + kb + 4) : z;
        float4 lo1 = v0 ? *(const float4*)(xr[1] + kb)     : z;
        float4 hi1 = v1 ? *(const float4*)(xr[1] + kb + 4) : z;
        s16x8 a0 = cvt8f(lo0, hi0);
        s16x8 a1 = cvt8f(lo1, hi1);
        // A batch 2 loads issued before batch-1 MFMAs (latency overlap)
        float4 lo2 = v0 ? *(const float4*)(xr[2] + kb)     : z;
        float4 hi2 = v1 ? *(const float4*)(xr[2] + kb + 4) : z;
        float4 lo3 = v0 ? *(const float4*)(xr[3] + kb)     : z;
        float4 hi3 = v1 ? *(const float4*)(xr[3] + kb + 4) : z;
        #pragma unroll
        for (int tt = 0; tt < 4; ++tt) {
            acc[tt][0] = MFMA(a0, bf[tt], acc[tt][0]);
            acc[tt][1] = MFMA(a1, bf[tt], acc[tt][1]);
        }
        s16x8 a2 = cvt8f(lo2, hi2);
        s16x8 a3 = cvt8f(lo3, hi3);
        #pragma unroll
        for (int tt = 0; tt < 4; ++tt) {
            acc[tt][2] = MFMA(a2, bf[tt], acc[tt][2]);
            acc[tt][3] = MFMA(a3, bf[tt], acc[tt][3]);
        }
    }

    if (d == 6) {
        // ---- leaf: recombine i/u/o through LDS, fuse gates ----
        __syncthreads();             // all waves done reading B
        #pragma unroll
        for (int tt = 0; tt < 4; ++tt) {
            int ct = wv + 8 * tt;
            if (ct < 30) {
                #pragma unroll
                for (int mt = 0; mt < 4; ++mt)
                    #pragma unroll
                    for (int r = 0; r < 4; ++r)
                        rs[(16*mt + 4*kg + r) * RSTR + ct * 16 + l15] = f2h_s(acc[tt][mt][r]);
            }
        }
        __syncthreads();
        {
            int rr = t & 63, c0 = t >> 6;        // 64 rows x 8 col-phases
            int lcl = local0 + rr, b = lcl >> 6, s = lcl & 63;
            const short* rp = &rs[rr * RSTR];
            size_t hb = ((size_t)b * NN + 63 + s) * HD;
            size_t cb = ((size_t)b * 126 + 62 + s) * HD;
            #pragma unroll
            for (int j = 0; j < 19; ++j) {
                int c = c0 + 8 * j;
                if (c < HD) {
                    float ig = h2f_s(rp[c])       + biuo[c];
                    float ug = h2f_s(rp[160 + c]) + biuo[HD + c];
                    float og = h2f_s(rp[320 + c]) + biuo[2*HD + c];
                    float cn = sig_(ig) * tanh_(ug);
                    float hn = sig_(og) * tanh_(cn);
                    h_all[hb + c] = hn;
                    c_all[cb + c] = (f16)cn;
                }
            }
        }
    } else {
        // ---- internal: write pre-activations to iuo ring (f16) ----
        #pragma unroll
        for (int tt = 0; tt < 4; ++tt) {
            int ct = wv + 8 * tt;
            if (ct >= 30) continue;
            int g = ct / 10;
            int cig = (ct - g * 10) * 16 + l15;
            if (cig < HD) {
                #pragma unroll
                for (int mt = 0; mt < 4; ++mt)
                    #pragma unroll
                    for (int r = 0; r < 4; ++r) {
                        int lcl = local0 + 16*mt + 4*kg + r;
                        int b = lcl >> lg, s = lcl & mask;
                        iuo_all[((size_t)b*63 + start + s) * 456 + 152*g + cig] =
                            (f16)acc[tt][mt][r];
                    }
            }
        }
    }
}

// -------- light: per internal level. 32 parents/block, 5 waves x 2 col-triples --------
__global__ __launch_bounds__(LNT, 4)
void lvl_light(const short* __restrict__ Ubf, const short* __restrict__ Fbf,
               const float* __restrict__ biuo, const float* __restrict__ Ufb,
               const f16* __restrict__ iuo_all, f16* __restrict__ c_all,
               float* __restrict__ h_all, int start, int lg, int cstart)
{
    __shared__ short chs[2][32][CSTR];    // [child][parent][k] bf16
    __shared__ short hts[32][CSTR];       // h_tilda (child sum), computed once
    __shared__ short fgs[5][64][34];      // per-wave f-gates [child-row][2x16 cols]

    const int t = threadIdx.x;
    const int wv = t >> 6, ln = t & 63, l15 = ln & 15, kg = ln >> 4;
    const int row0 = blockIdx.x * 32;
    const int mask = (1 << lg) - 1;
    int ct0 = 16 * (2*wv)     + l15;
    int ct1 = 16 * (2*wv + 1) + l15;

    // stage children h (fp32 -> bf16 LDS): rc=t&63 (plane,parent), part=t>>6 (32 k each)
    {
        int rc = t & 63, part = t >> 6;   // part 0..4 covers k [0,160)
        int plane = rc >> 5, lr = rc & 31;
        int row = row0 + lr, b = row >> lg, s = row & mask;
        const float* hp = h_all + ((size_t)b*NN + cstart + 2*s + plane) * HD;
        short* dst = &chs[plane][lr][part * 32];
        #pragma unroll
        for (int q = 0; q < 8; ++q) {
            int k = part * 32 + q * 4;
            s16x4 v = {0,0,0,0};
            if (k + 3 < HD) {
                float4 f = *(const float4*)(hp + k);
                v = cvt4(f.x, f.y, f.z, f.w);
            } else if (k < HD) {          // k == 148
                float2 f = *(const float2*)(hp + k);
                v = s16x4{ f2bf(f.x), f2bf(f.y), 0, 0 };
            }
            *(s16x4*)(dst + q * 4) = v;
        }
    }
    __syncthreads();

    // h_tilda once: 32 rows x 160 k / 320 threads = 16 shorts each
    {
        int r = t / 10, seg = t - 10 * r;      // r 0..31, seg 0..9
        int k0 = seg * 16;
        s16x8 h0a = *(const s16x8*)&chs[0][r][k0];
        s16x8 h0b = *(const s16x8*)&chs[0][r][k0 + 8];
        s16x8 h1a = *(const s16x8*)&chs[1][r][k0];
        s16x8 h1b = *(const s16x8*)&chs[1][r][k0 + 8];
        s16x8 oa, ob;
        #pragma unroll
        for (int e = 0; e < 8; ++e) {
            oa[e] = f2bf(bf2f(h0a[e]) + bf2f(h1a[e]));
            ob[e] = f2bf(bf2f(h0b[e]) + bf2f(h1b[e]));
        }
        *(s16x8*)&hts[r][k0]     = oa;
        *(s16x8*)&hts[r][k0 + 8] = ob;
    }

    // F phase: f = sigmoid(ch @ F^T + b)
    f32x4 facc[4][2] = {};                // [rt][tt]
    #pragma unroll
    for (int kc = 0; kc < 5; ++kc) {
        int ka = kc * 32 + kg * 8;
        s16x8 af[4];
        #pragma unroll
        for (int rt = 0; rt < 4; ++rt) {
            const short* p = &chs[rt >> 1][(rt & 1) * 16 + l15][ka];
            af[rt] = cat(*(const s16x4*)p, *(const s16x4*)(p + 4));
        }
        #pragma unroll
        for (int tt = 0; tt < 2; ++tt) {
            int ct = tt ? ct1 : ct0;
            s16x8 bf = *(const s16x8*)(Fbf + (size_t)ct * 160 + ka);
            #pragma unroll
            for (int rt = 0; rt < 4; ++rt)
                facc[rt][tt] = MFMA(af[rt], bf, facc[rt][tt]);
        }
    }
    #pragma unroll
    for (int tt = 0; tt < 2; ++tt) {
        int ct = tt ? ct1 : ct0;
        float fb_ = (ct < HD) ? Ufb[ct] : 0.0f;
        #pragma unroll
        for (int rt = 0; rt < 4; ++rt)
            #pragma unroll
            for (int r = 0; r < 4; ++r)
                fgs[wv][rt*16 + 4*kg + r][tt*16 + l15] = f2bf(sig_(facc[rt][tt][r] + fb_));
    }
    __syncthreads();   // fgs + hts visible

    // U phase: acc = h_tilda @ U^T (A-frags straight from hts)
    f32x4 acc[2][2][3] = {};              // [mt][tt][g]
    #pragma unroll
    for (int kc = 0; kc < 5; ++kc) {
        int ka = kc * 32 + kg * 8;
        s16x8 hs[2];
        #pragma unroll
        for (int mt = 0; mt < 2; ++mt) {
            const short* p = &hts[16*mt + l15][ka];
            hs[mt] = cat(*(const s16x4*)p, *(const s16x4*)(p + 4));
        }
        #pragma unroll
        for (int tt = 0; tt < 2; ++tt) {
            int ct = tt ? ct1 : ct0;
            #pragma unroll
            for (int g = 0; g < 3; ++g) {
                s16x8 bf = *(const s16x8*)(Ubf + (size_t)(g*160 + ct) * 160 + ka);
                #pragma unroll
                for (int mt = 0; mt < 2; ++mt)
                    acc[mt][tt][g] = MFMA(hs[mt], bf, acc[mt][tt][g]);
            }
        }
    }

    // epilogue
    #pragma unroll
    for (int tt = 0; tt < 2; ++tt) {
        int c = tt ? ct1 : ct0;
        if (c >= HD) continue;
        float bi = biuo[c], bu = biuo[HD + c], bo = biuo[2*HD + c];
        #pragma unroll
        for (int mt = 0; mt < 2; ++mt)
            #pragma unroll
            for (int r = 0; r < 4; ++r) {
                int pl = 16*mt + 4*kg + r;
                int row = row0 + pl, b = row >> lg, s = row & mask;
                const f16* ip = iuo_all + ((size_t)b*63 + start + s) * 456;
                float ig = (float)ip[c]       + bi + acc[mt][tt][0][r];
                float ug = (float)ip[152 + c] + bu + acc[mt][tt][1][r];
                float og = (float)ip[304 + c] + bo + acc[mt][tt][2][r];
                float f0 = bf2f(fgs[wv][pl][tt*16 + l15]);
                float f1 = bf2f(fgs[wv][32 + pl][tt*16 + l15]);
                size_t ci = (size_t)b*126 + (cstart + 2*s - 1);
                float c0 = (float)c_all[ci * HD + c];
                float c1 = (float)c_all[(ci + 1) * HD + c];
                float cn = sig_(ig) * tanh_(ug) + f0*c0 + f1*c1;
                float hn = sig_(og) * tanh_(cn);
                h_all[((size_t)b*NN + start + s) * HD + c] = hn;
                if (start > 0)   // root c never read
                    c_all[((size_t)b*126 + start + s - 1) * HD + c] = (f16)cn;
            }
    }
}

extern "C" void kernel_launch(void* const* d_in, const int* in_sizes, int n_in,
                              void* d_out, int out_size, void* d_ws, size_t ws_size,
                              hipStream_t stream) {
    const float* x    = (const float*)d_in[0];
    const float* Wiuo = (const float*)d_in[1];
    const float* Uiuo = (const float*)d_in[2];
    const float* biuo = (const float*)d_in[3];
    const float* Ufw  = (const float*)d_in[4];
    const float* Ufb  = (const float*)d_in[5];
    float* h = (float*)d_out;

    f16* c_all   = (f16*)d_ws;
    f16* iuo_all = c_all + C_N;
    short* slabs = (short*)(iuo_all + IUO_N);
    const short* Wsl = slabs;
    const short* Ubf = slabs + W_SH;
    const short* Fbf = slabs + W_SH + U_SH;

    (void)hipFuncSetAttribute((const void*)big_gemm,
                              hipFuncAttributeMaxDynamicSharedMemorySize, 160 * 1024);

    prep_w<<<(W_SH + U_SH + F_SH + 255) / 256, 256, 0, stream>>>(Wiuo, Uiuo, Ufw, slabs);

    big_gemm<<<8128, GNT, GEMM_LDS, stream>>>(x, Wsl, biuo, h, c_all, iuo_all);

    for (int d = 5; d >= 0; --d) {
        const int start = (1 << d) - 1, cstart = (1 << (d+1)) - 1;
        lvl_light<<<128 << d, LNT, 0, stream>>>(Ubf, Fbf, biuo, Ufb, iuo_all, c_all, h,
                                                start, d, cstart);
    }
}